// Round 4
// baseline (2849.361 us; speedup 1.0000x reference)
//
#include <hip/hip_runtime.h>
#include <math.h>

// TfLSTM: x[512,256,128] -> LSTM(100, relu) -> LSTM(128, relu, last) -> Dense(19) -> softmax
// Round 4: same split design as round 3 BUT all per-thread weight/accumulator
// arrays replaced by macro-expanded individual ext_vector(4) SSA values.
// Round-3 evidence: u0[100]/u1[100] allocas were NEVER promoted (VGPR_Count=128,
// +140MB scratch WRITE traffic, rec1=1580us). SSA values force register alloc.
//   ws layout (floats): zxbuf 209.7MB | h1seq 52.4MB | cbuf/hbuf/h2buf 0.26MB ea.

#define T_SEQ 256
#define BATCH 512
#define IN_DIM 128
#define H1 100
#define H2 128
#define NCLS 19

typedef float f4v __attribute__((ext_vector_type(4)));

__device__ __forceinline__ float sigmoidf_(float x) {
    return 1.0f / (1.0f + __expf(-x));
}
__device__ __forceinline__ float hsum4_(f4v v) {
    return (v.x + v.y) + (v.z + v.w);
}

#define REP8(M)  M(0) M(1) M(2) M(3) M(4) M(5) M(6) M(7)
#define REP25(M) M(0) M(1) M(2) M(3) M(4) M(5) M(6) M(7) M(8) M(9) M(10) M(11) \
                 M(12) M(13) M(14) M(15) M(16) M(17) M(18) M(19) M(20) M(21) M(22) M(23) M(24)

// =================== projection GEMM ===================
// out[orow][n] = bias[n] + sum_k A[r][k] * W[k][n]
// Tile 128x128, micro 8x8 (16 f4v SSA accumulators), k-chunks of 32.
template<int K, int N, bool SWAP>
__global__ __launch_bounds__(256, 2)
void proj_kernel(const float* __restrict__ A, const float* __restrict__ W,
                 const float* __restrict__ bias, float* __restrict__ out)
{
    constexpr int LD = 132;  // padded LDS stride
    __shared__ __align__(16) float As[32 * LD];  // [k][row]
    __shared__ __align__(16) float Ws[32 * LD];  // [k][col]
    const int tid = threadIdx.x;
    const int r0 = blockIdx.x * 128;
    const int c0 = blockIdx.y * 128;
    const int ty = tid >> 4, tx = tid & 15;

#define PACC(i) f4v accL##i = {0.f,0.f,0.f,0.f}; f4v accR##i = {0.f,0.f,0.f,0.f};
    REP8(PACC)
#undef PACC

    for (int kk = 0; kk < K; kk += 32) {
        __syncthreads();
        // stage A chunk transposed: As[k][row]
#pragma unroll
        for (int i = 0; i < 4; ++i) {
            int idx = tid + i * 256;          // 1024 float4 slots: 128 rows x 8 kgroups
            int row = idx >> 3, kg = idx & 7;
            int k = kk + kg * 4;
            f4v v = {0.f, 0.f, 0.f, 0.f};
            if (k < K) v = *(const f4v*)&A[(size_t)(r0 + row) * K + k];
            As[(kg * 4 + 0) * LD + row] = v.x;
            As[(kg * 4 + 1) * LD + row] = v.y;
            As[(kg * 4 + 2) * LD + row] = v.z;
            As[(kg * 4 + 3) * LD + row] = v.w;
        }
        // stage W chunk: Ws[k][col]
#pragma unroll
        for (int i = 0; i < 4; ++i) {
            int idx = tid + i * 256;          // 1024 float4 slots: 32 k x 32 colgroups
            int k = idx >> 5, cg = idx & 31;
            int gk = kk + k, gc = c0 + cg * 4;
            f4v v = {0.f, 0.f, 0.f, 0.f};
            if (gk < K && gc < N) v = *(const f4v*)&W[(size_t)gk * N + gc];
            *(f4v*)&Ws[k * LD + cg * 4] = v;
        }
        __syncthreads();
#pragma unroll
        for (int k = 0; k < 32; ++k) {
            f4v av0 = *(const f4v*)&As[k * LD + ty * 8];
            f4v av1 = *(const f4v*)&As[k * LD + ty * 8 + 4];
            f4v b0v = *(const f4v*)&Ws[k * LD + tx * 8];
            f4v b1v = *(const f4v*)&Ws[k * LD + tx * 8 + 4];
#define PFMA(i, s) accL##i += (s) * b0v; accR##i += (s) * b1v;
            PFMA(0, av0.x) PFMA(1, av0.y) PFMA(2, av0.z) PFMA(3, av0.w)
            PFMA(4, av1.x) PFMA(5, av1.y) PFMA(6, av1.z) PFMA(7, av1.w)
#undef PFMA
        }
    }

    // epilogue: + bias, guarded f4 stores
    const int cb = c0 + tx * 8;
    float b0 = (cb + 0 < N) ? bias[cb + 0] : 0.f;
    float b1 = (cb + 1 < N) ? bias[cb + 1] : 0.f;
    float b2 = (cb + 2 < N) ? bias[cb + 2] : 0.f;
    float b3 = (cb + 3 < N) ? bias[cb + 3] : 0.f;
    float b4 = (cb + 4 < N) ? bias[cb + 4] : 0.f;
    float b5 = (cb + 5 < N) ? bias[cb + 5] : 0.f;
    float b6 = (cb + 6 < N) ? bias[cb + 6] : 0.f;
    float b7 = (cb + 7 < N) ? bias[cb + 7] : 0.f;
    f4v bL = {b0, b1, b2, b3};
    f4v bR = {b4, b5, b6, b7};
#define PST(i) { \
        int r = r0 + ty * 8 + i; \
        size_t orow = SWAP ? ((size_t)(r & 255) * BATCH + (r >> 8)) : (size_t)r; \
        if (cb < N)     { f4v v = accL##i + bL; *(f4v*)&out[orow * N + cb] = v; } \
        if (cb + 4 < N) { f4v v = accR##i + bR; *(f4v*)&out[orow * N + cb + 4] = v; } }
    REP8(PST)
#undef PST
}

// =================== recurrence, layer 1 ===================
// z = zx[t] (bias in zx) + h @ U1. Thread k<200 owns cols {k, k+200}
// (i,g for k<100; f,o for k>=100). 50 f4v SSA weights (200 VGPRs).
__global__ __launch_bounds__(256, 2)
void rec1_kernel(const float* __restrict__ zx,   // [T][B][400]
                 const float* __restrict__ U1,   // [100][400]
                 float* __restrict__ h1seq)      // [T][B][100]
{
    const int row = blockIdx.x;
    const int k = threadIdx.x;
    __shared__ __align__(16) float hs[H1];
    __shared__ __align__(8) float fo[2 * H1];

    const int kk = (k < 200) ? k : 0;   // clamp: lanes >=200 compute garbage, never store
    const int c0 = kk, c1 = kk + 200;

    // one-time weight load into 50 f4v SSA values (stride-400 gathers, coalesced per lane)
#define R1_LD(i) \
    f4v u0_##i, u1_##i; { \
        const float* p = U1 + (4 * i) * 400; \
        u0_##i = (f4v){p[c0], p[400 + c0], p[800 + c0], p[1200 + c0]}; \
        u1_##i = (f4v){p[c1], p[400 + c1], p[800 + c1], p[1200 + c1]}; }
    REP25(R1_LD)
#undef R1_LD

    if (k < H1) hs[k] = 0.0f;
    float cst = 0.0f;
    float zc0 = zx[(size_t)row * 400 + c0];
    float zc1 = zx[(size_t)row * 400 + c1];
    __syncthreads();

    for (int t = 0; t < T_SEQ; ++t) {
        // prefetch next step's zx
        int tn = (t + 1 < T_SEQ) ? t + 1 : t;
        const float* pz = &zx[((size_t)tn * BATCH + row) * 400];
        float zn0 = pz[c0];
        float zn1 = pz[c1];

        f4v s0 = {0.f, 0.f, 0.f, 0.f};
        f4v s1 = {0.f, 0.f, 0.f, 0.f};
#define R1_FMA(i) { f4v hv = *(const f4v*)&hs[4 * i]; s0 += hv * u0_##i; s1 += hv * u1_##i; }
        REP25(R1_FMA)
#undef R1_FMA
        float a0 = sigmoidf_(zc0 + hsum4_(s0));                    // i or f
        float a1h = zc1 + hsum4_(s1);
        float a1 = (k < H1) ? fmaxf(a1h, 0.0f) : sigmoidf_(a1h);   // g (relu) or o
        if (k >= H1 && k < 200) *(float2*)&fo[2 * (k - H1)] = make_float2(a0, a1);
        __syncthreads();

        if (k < H1) {
            float2 f_o = *(const float2*)&fo[2 * k];
            cst = f_o.x * cst + a0 * a1;          // c = f*c + i*g
            float h = f_o.y * fmaxf(cst, 0.0f);   // h = o*relu(c)
            hs[k] = h;
            h1seq[((size_t)t * BATCH + row) * H1 + k] = h;
        }
        __syncthreads();
        zc0 = zn0;
        zc1 = zn1;
    }
}

// =================== recurrence, layer 2 (time-chunked) ===================
// 4-way k-split: thread (kq=tid>>7, cl=tid&127) covers k in [kq*32,kq*32+32)
// for cols {cl, cl+128, cl+256, cl+384}. 32 f4v SSA weights (128 VGPRs).
template<bool INIT, bool LAST>
__global__ __launch_bounds__(512, 2)
void rec2_chunk(const float* __restrict__ zx,    // [tlen][B][512] (bias included)
                const float* __restrict__ U2,    // [128][512]
                float* __restrict__ cbuf,        // [B][128]
                float* __restrict__ hbuf,        // [B][128]
                float* __restrict__ h2out,       // [B][128] (used when LAST)
                int tlen)
{
    const int row = blockIdx.x;
    const int tid = threadIdx.x;   // 0..511
    const int kq = tid >> 7;
    const int cl = tid & 127;
    __shared__ __align__(16) float hs[H2];
    __shared__ float zp[4 * 512];
    __shared__ float za[512];

#define R2_LD(j) \
    f4v w0_##j, w1_##j, w2_##j, w3_##j; { \
        const float* p = U2 + (size_t)(kq * 32 + 4 * j) * 512 + cl; \
        w0_##j = (f4v){p[0],   p[512],       p[1024],       p[1536]}; \
        w1_##j = (f4v){p[128], p[512 + 128], p[1024 + 128], p[1536 + 128]}; \
        w2_##j = (f4v){p[256], p[512 + 256], p[1024 + 256], p[1536 + 256]}; \
        w3_##j = (f4v){p[384], p[512 + 384], p[1024 + 384], p[1536 + 384]}; }
    REP8(R2_LD)
#undef R2_LD

    float cst = 0.0f;
    if (tid < H2) {
        if (INIT) {
            hs[tid] = 0.0f;
        } else {
            hs[tid] = hbuf[(size_t)row * H2 + tid];
            cst = cbuf[(size_t)row * H2 + tid];
        }
    }
    float zc = zx[(size_t)row * 512 + tid];
    __syncthreads();

    for (int t = 0; t < tlen; ++t) {
        int tn = (t + 1 < tlen) ? t + 1 : t;
        float zn = zx[((size_t)tn * BATCH + row) * 512 + tid];

        f4v s0 = {0.f, 0.f, 0.f, 0.f};
        f4v s1 = {0.f, 0.f, 0.f, 0.f};
        f4v s2 = {0.f, 0.f, 0.f, 0.f};
        f4v s3 = {0.f, 0.f, 0.f, 0.f};
#define R2_FMA(j) { f4v hv = *(const f4v*)&hs[kq * 32 + 4 * j]; \
        s0 += hv * w0_##j; s1 += hv * w1_##j; s2 += hv * w2_##j; s3 += hv * w3_##j; }
        REP8(R2_FMA)
#undef R2_FMA
        zp[kq * 512 + cl]       = hsum4_(s0);
        zp[kq * 512 + cl + 128] = hsum4_(s1);
        zp[kq * 512 + cl + 256] = hsum4_(s2);
        zp[kq * 512 + cl + 384] = hsum4_(s3);
        __syncthreads();

        float z = zc + (zp[tid] + zp[512 + tid]) + (zp[1024 + tid] + zp[1536 + tid]);
        float a = (tid >= 2 * H2 && tid < 3 * H2) ? fmaxf(z, 0.0f) : sigmoidf_(z);
        za[tid] = a;
        __syncthreads();

        if (tid < H2) {
            float i = za[tid], f = za[tid + 128], g = za[tid + 256], o = za[tid + 384];
            cst = f * cst + i * g;
            hs[tid] = o * fmaxf(cst, 0.0f);
        }
        __syncthreads();
        zc = zn;
    }

    if (tid < H2) {
        float h = hs[tid];
        cbuf[(size_t)row * H2 + tid] = cst;
        hbuf[(size_t)row * H2 + tid] = h;
        if (LAST) h2out[(size_t)row * H2 + tid] = h;
    }
}

// =================== dense + softmax ===================
__global__ __launch_bounds__(64, 1)
void dense_softmax_kernel(const float* __restrict__ h2, const float* __restrict__ Wd,
                          const float* __restrict__ bd, float* __restrict__ out)
{
    const int b = blockIdx.x;
    const int k = threadIdx.x;
    __shared__ __align__(16) float hsm[H2];
    if (k < H2 / 4) ((f4v*)hsm)[k] = ((const f4v*)(h2 + (size_t)b * H2))[k];
    __syncthreads();

    float logit = -1e30f;
    if (k < NCLS) {
        float acc = bd[k];
#pragma unroll
        for (int d = 0; d < H2; ++d) acc += hsm[d] * Wd[d * NCLS + k];
        logit = acc;
    }
    float m = logit;
#pragma unroll
    for (int off = 32; off >= 1; off >>= 1) m = fmaxf(m, __shfl_xor(m, off, 64));
    float e = (k < NCLS) ? __expf(logit - m) : 0.0f;
    float s = e;
#pragma unroll
    for (int off = 32; off >= 1; off >>= 1) s += __shfl_xor(s, off, 64);
    if (k < NCLS) out[(size_t)b * NCLS + k] = e / s;
}

// =================== fallback (round-1) kernels ===================
__global__ __launch_bounds__(448, 1)
void lstm1_fb(const float* __restrict__ x, const float* __restrict__ W1,
              const float* __restrict__ U1, const float* __restrict__ b1,
              float* __restrict__ h1out)
{
    const int b = blockIdx.x;
    const int k = threadIdx.x;
    __shared__ __align__(16) float xs[IN_DIM];
    __shared__ __align__(16) float hs[H1];
    __shared__ __align__(16) float zs[4 * H1];
    float w1r[IN_DIM];
    float u1r[H1];
    float bias = 0.0f;
    if (k < 4 * H1) {
        bias = b1[k];
#pragma unroll
        for (int d = 0; d < IN_DIM; ++d) w1r[d] = W1[d * (4 * H1) + k];
#pragma unroll
        for (int j = 0; j < H1; ++j) u1r[j] = U1[j * (4 * H1) + k];
    }
    if (k < H1) hs[k] = 0.0f;
    if (k < IN_DIM / 4)
        ((float4*)xs)[k] = ((const float4*)(x + ((size_t)b * T_SEQ) * IN_DIM))[k];
    float c = 0.0f;
    __syncthreads();
    for (int t = 0; t < T_SEQ; ++t) {
        if (k < 4 * H1) {
            float acc0 = bias, acc1 = 0.f, acc2 = 0.f, acc3 = 0.f;
#pragma unroll
            for (int q = 0; q < IN_DIM / 4; ++q) {
                float4 xv = ((const float4*)xs)[q];
                acc0 += xv.x * w1r[4 * q]; acc1 += xv.y * w1r[4 * q + 1];
                acc2 += xv.z * w1r[4 * q + 2]; acc3 += xv.w * w1r[4 * q + 3];
            }
#pragma unroll
            for (int q = 0; q < H1 / 4; ++q) {
                float4 hv = ((const float4*)hs)[q];
                acc0 += hv.x * u1r[4 * q]; acc1 += hv.y * u1r[4 * q + 1];
                acc2 += hv.z * u1r[4 * q + 2]; acc3 += hv.w * u1r[4 * q + 3];
            }
            float zv = (acc0 + acc1) + (acc2 + acc3);
            zs[k] = (k >= 2 * H1 && k < 3 * H1) ? fmaxf(zv, 0.0f) : sigmoidf_(zv);
        }
        __syncthreads();
        if (k < H1) {
            float i = zs[k], f = zs[k + H1], g = zs[k + 2 * H1], o = zs[k + 3 * H1];
            c = f * c + i * g;
            float h = o * fmaxf(c, 0.0f);
            hs[k] = h;
            h1out[((size_t)t * BATCH + b) * H1 + k] = h;
        }
        int tn = t + 1;
        if (tn < T_SEQ && k < IN_DIM / 4)
            ((float4*)xs)[k] = ((const float4*)(x + ((size_t)b * T_SEQ + tn) * IN_DIM))[k];
        __syncthreads();
    }
}

__global__ __launch_bounds__(512, 1)
void lstm2_fb(const float* __restrict__ h1in, const float* __restrict__ W2,
              const float* __restrict__ U2, const float* __restrict__ b2,
              float* __restrict__ h2out)
{
    const int b = blockIdx.x;
    const int k = threadIdx.x;
    __shared__ __align__(16) float ps[H1];
    __shared__ __align__(16) float hs[H2];
    __shared__ __align__(16) float zs[4 * H2];
    float w2r[H1];
    float u2r[H2];
    float bias = b2[k];
#pragma unroll
    for (int j = 0; j < H1; ++j) w2r[j] = W2[j * (4 * H2) + k];
#pragma unroll
    for (int j = 0; j < H2; ++j) u2r[j] = U2[j * (4 * H2) + k];
    if (k < H2) hs[k] = 0.0f;
    if (k < H1 / 4)
        ((float4*)ps)[k] = ((const float4*)(h1in + (size_t)b * H1))[k];
    float c = 0.0f;
    float hlast = 0.0f;
    __syncthreads();
    for (int t = 0; t < T_SEQ; ++t) {
        float acc0 = bias, acc1 = 0.f, acc2 = 0.f, acc3 = 0.f;
#pragma unroll
        for (int q = 0; q < H1 / 4; ++q) {
            float4 pv = ((const float4*)ps)[q];
            acc0 += pv.x * w2r[4 * q]; acc1 += pv.y * w2r[4 * q + 1];
            acc2 += pv.z * w2r[4 * q + 2]; acc3 += pv.w * w2r[4 * q + 3];
        }
#pragma unroll
        for (int q = 0; q < H2 / 4; ++q) {
            float4 hv = ((const float4*)hs)[q];
            acc0 += hv.x * u2r[4 * q]; acc1 += hv.y * u2r[4 * q + 1];
            acc2 += hv.z * u2r[4 * q + 2]; acc3 += hv.w * u2r[4 * q + 3];
        }
        float zv = (acc0 + acc1) + (acc2 + acc3);
        zs[k] = (k >= 2 * H2 && k < 3 * H2) ? fmaxf(zv, 0.0f) : sigmoidf_(zv);
        __syncthreads();
        if (k < H2) {
            float i = zs[k], f = zs[k + H2], g = zs[k + 2 * H2], o = zs[k + 3 * H2];
            c = f * c + i * g;
            hlast = o * fmaxf(c, 0.0f);
            hs[k] = hlast;
        }
        int tn = t + 1;
        if (tn < T_SEQ && k < H1 / 4)
            ((float4*)ps)[k] = ((const float4*)(h1in + ((size_t)tn * BATCH + b) * H1))[k];
        __syncthreads();
    }
    if (k < H2) h2out[(size_t)b * H2 + k] = hlast;
}

extern "C" void kernel_launch(void* const* d_in, const int* in_sizes, int n_in,
                              void* d_out, int out_size, void* d_ws, size_t ws_size,
                              hipStream_t stream) {
    const float* x  = (const float*)d_in[0];
    const float* W1 = (const float*)d_in[1];
    const float* U1 = (const float*)d_in[2];
    const float* b1 = (const float*)d_in[3];
    const float* W2 = (const float*)d_in[4];
    const float* U2 = (const float*)d_in[5];
    const float* b2 = (const float*)d_in[6];
    const float* Wd = (const float*)d_in[7];
    const float* bd = (const float*)d_in[8];
    float* out = (float*)d_out;

    const size_t zx_elems = (size_t)T_SEQ * BATCH * 400;   // 52428800
    const size_t h1_elems = (size_t)T_SEQ * BATCH * H1;    // 13107200
    const size_t st_elems = (size_t)BATCH * H2;            // 65536
    const size_t need = (zx_elems + h1_elems + 3 * st_elems) * sizeof(float);  // 262.93 MB

    if (ws_size >= need) {
        float* zxbuf = (float*)d_ws;
        float* h1buf = zxbuf + zx_elems;
        float* cbuf  = h1buf + h1_elems;
        float* hbuf  = cbuf + st_elems;
        float* h2buf = hbuf + st_elems;
        const int TC = T_SEQ / 2;   // 128-step chunks

        // zx1 = x @ W1 + b1 -> [T][B][400]
        hipLaunchKernelGGL((proj_kernel<IN_DIM, 4 * H1, true>), dim3(1024, 4), dim3(256), 0, stream,
                           x, W1, b1, zxbuf);
        hipLaunchKernelGGL(rec1_kernel, dim3(BATCH), dim3(256), 0, stream,
                           zxbuf, U1, h1buf);
        // ---- layer 2, chunk A (t = 0..127): zx2 chunk overwrites zx1 region ----
        hipLaunchKernelGGL((proj_kernel<H1, 4 * H2, false>), dim3(512, 4), dim3(256), 0, stream,
                           h1buf, W2, b2, zxbuf);
        hipLaunchKernelGGL((rec2_chunk<true, false>), dim3(BATCH), dim3(512), 0, stream,
                           zxbuf, U2, cbuf, hbuf, h2buf, TC);
        // ---- layer 2, chunk B (t = 128..255) ----
        hipLaunchKernelGGL((proj_kernel<H1, 4 * H2, false>), dim3(512, 4), dim3(256), 0, stream,
                           h1buf + (size_t)TC * BATCH * H1, W2, b2, zxbuf);
        hipLaunchKernelGGL((rec2_chunk<false, true>), dim3(BATCH), dim3(512), 0, stream,
                           zxbuf, U2, cbuf, hbuf, h2buf, TC);

        hipLaunchKernelGGL(dense_softmax_kernel, dim3(BATCH), dim3(64), 0, stream,
                           h2buf, Wd, bd, out);
    } else {
        // fallback: round-1 fused kernels (needs ~52.7 MB)
        float* h1buf = (float*)d_ws;
        float* h2buf = h1buf + h1_elems;
        hipLaunchKernelGGL(lstm1_fb, dim3(BATCH), dim3(448), 0, stream, x, W1, U1, b1, h1buf);
        hipLaunchKernelGGL(lstm2_fb, dim3(BATCH), dim3(512), 0, stream, h1buf, W2, U2, b2, h2buf);
        hipLaunchKernelGGL(dense_softmax_kernel, dim3(BATCH), dim3(64), 0, stream, h2buf, Wd, bd, out);
    }
}

// Round 5
// 1299.610 us; speedup vs baseline: 2.1925x; 2.1925x over previous
//
#include <hip/hip_runtime.h>
#include <math.h>

// TfLSTM: x[512,256,128] -> LSTM(100, relu) -> LSTM(128, relu, last) -> Dense(19) -> softmax
// Round 5: round-4 SSA design + amdgpu_waves_per_eu to fix the register
// allocator's occupancy TARGET (r4 evidence: SSA weights were rematerialized
// into the loop -> FETCH 710MB, VALUBusy 6%, VGPR capped at the default
// 4-waves/EU 128-reg budget). waves_per_eu(1,1) on rec1 (4-wave block) gives a
// 512-reg budget; (2,2) on rec2 (8-wave block) gives 256.
//   ws layout (floats): zxbuf 209.7MB | h1seq 52.4MB | cbuf/hbuf/h2buf 0.26MB ea.

#define T_SEQ 256
#define BATCH 512
#define IN_DIM 128
#define H1 100
#define H2 128
#define NCLS 19

typedef float f4v __attribute__((ext_vector_type(4)));

__device__ __forceinline__ float sigmoidf_(float x) {
    return 1.0f / (1.0f + __expf(-x));
}
__device__ __forceinline__ float hsum4_(f4v v) {
    return (v.x + v.y) + (v.z + v.w);
}

#define REP8(M)  M(0) M(1) M(2) M(3) M(4) M(5) M(6) M(7)
#define REP25(M) M(0) M(1) M(2) M(3) M(4) M(5) M(6) M(7) M(8) M(9) M(10) M(11) \
                 M(12) M(13) M(14) M(15) M(16) M(17) M(18) M(19) M(20) M(21) M(22) M(23) M(24)

// =================== projection GEMM ===================
// out[orow][n] = bias[n] + sum_k A[r][k] * W[k][n]
// Tile 128x128, micro 8x8 (16 f4v SSA accumulators), k-chunks of 32.
template<int K, int N, bool SWAP>
__global__ __launch_bounds__(256, 2)
void proj_kernel(const float* __restrict__ A, const float* __restrict__ W,
                 const float* __restrict__ bias, float* __restrict__ out)
{
    constexpr int LD = 132;  // padded LDS stride
    __shared__ __align__(16) float As[32 * LD];  // [k][row]
    __shared__ __align__(16) float Ws[32 * LD];  // [k][col]
    const int tid = threadIdx.x;
    const int r0 = blockIdx.x * 128;
    const int c0 = blockIdx.y * 128;
    const int ty = tid >> 4, tx = tid & 15;

#define PACC(i) f4v accL##i = {0.f,0.f,0.f,0.f}; f4v accR##i = {0.f,0.f,0.f,0.f};
    REP8(PACC)
#undef PACC

    for (int kk = 0; kk < K; kk += 32) {
        __syncthreads();
        // stage A chunk transposed: As[k][row]
#pragma unroll
        for (int i = 0; i < 4; ++i) {
            int idx = tid + i * 256;          // 1024 float4 slots: 128 rows x 8 kgroups
            int row = idx >> 3, kg = idx & 7;
            int k = kk + kg * 4;
            f4v v = {0.f, 0.f, 0.f, 0.f};
            if (k < K) v = *(const f4v*)&A[(size_t)(r0 + row) * K + k];
            As[(kg * 4 + 0) * LD + row] = v.x;
            As[(kg * 4 + 1) * LD + row] = v.y;
            As[(kg * 4 + 2) * LD + row] = v.z;
            As[(kg * 4 + 3) * LD + row] = v.w;
        }
        // stage W chunk: Ws[k][col]
#pragma unroll
        for (int i = 0; i < 4; ++i) {
            int idx = tid + i * 256;          // 1024 float4 slots: 32 k x 32 colgroups
            int k = idx >> 5, cg = idx & 31;
            int gk = kk + k, gc = c0 + cg * 4;
            f4v v = {0.f, 0.f, 0.f, 0.f};
            if (gk < K && gc < N) v = *(const f4v*)&W[(size_t)gk * N + gc];
            *(f4v*)&Ws[k * LD + cg * 4] = v;
        }
        __syncthreads();
#pragma unroll
        for (int k = 0; k < 32; ++k) {
            f4v av0 = *(const f4v*)&As[k * LD + ty * 8];
            f4v av1 = *(const f4v*)&As[k * LD + ty * 8 + 4];
            f4v b0v = *(const f4v*)&Ws[k * LD + tx * 8];
            f4v b1v = *(const f4v*)&Ws[k * LD + tx * 8 + 4];
#define PFMA(i, s) accL##i += (s) * b0v; accR##i += (s) * b1v;
            PFMA(0, av0.x) PFMA(1, av0.y) PFMA(2, av0.z) PFMA(3, av0.w)
            PFMA(4, av1.x) PFMA(5, av1.y) PFMA(6, av1.z) PFMA(7, av1.w)
#undef PFMA
        }
    }

    // epilogue: + bias, guarded f4 stores
    const int cb = c0 + tx * 8;
    float b0 = (cb + 0 < N) ? bias[cb + 0] : 0.f;
    float b1 = (cb + 1 < N) ? bias[cb + 1] : 0.f;
    float b2 = (cb + 2 < N) ? bias[cb + 2] : 0.f;
    float b3 = (cb + 3 < N) ? bias[cb + 3] : 0.f;
    float b4 = (cb + 4 < N) ? bias[cb + 4] : 0.f;
    float b5 = (cb + 5 < N) ? bias[cb + 5] : 0.f;
    float b6 = (cb + 6 < N) ? bias[cb + 6] : 0.f;
    float b7 = (cb + 7 < N) ? bias[cb + 7] : 0.f;
    f4v bL = {b0, b1, b2, b3};
    f4v bR = {b4, b5, b6, b7};
#define PST(i) { \
        int r = r0 + ty * 8 + i; \
        size_t orow = SWAP ? ((size_t)(r & 255) * BATCH + (r >> 8)) : (size_t)r; \
        if (cb < N)     { f4v v = accL##i + bL; *(f4v*)&out[orow * N + cb] = v; } \
        if (cb + 4 < N) { f4v v = accR##i + bR; *(f4v*)&out[orow * N + cb + 4] = v; } }
    REP8(PST)
#undef PST
}

// =================== recurrence, layer 1 ===================
// z = zx[t] (bias in zx) + h @ U1. Thread k<200 owns cols {k, k+200}
// (i,g for k<100; f,o for k>=100). 50 f4v SSA weights (200 VGPRs).
// waves_per_eu(1,1): 4-wave block -> 1 wave/EU -> 512-VGPR allocator budget,
// so the 200 weight regs stay LIVE (r4: default 4-wave target remat'ed them).
__global__ __launch_bounds__(256)
__attribute__((amdgpu_waves_per_eu(1, 1)))
void rec1_kernel(const float* __restrict__ zx,   // [T][B][400]
                 const float* __restrict__ U1,   // [100][400]
                 float* __restrict__ h1seq)      // [T][B][100]
{
    const int row = blockIdx.x;
    const int k = threadIdx.x;
    __shared__ __align__(16) float hs[H1];
    __shared__ __align__(8) float fo[2 * H1];

    const int kk = (k < 200) ? k : 0;   // clamp: lanes >=200 compute garbage, never store
    const int c0 = kk, c1 = kk + 200;

    // one-time weight load into 50 f4v SSA values
#define R1_LD(i) \
    f4v u0_##i, u1_##i; { \
        const float* p = U1 + (4 * i) * 400; \
        u0_##i = (f4v){p[c0], p[400 + c0], p[800 + c0], p[1200 + c0]}; \
        u1_##i = (f4v){p[c1], p[400 + c1], p[800 + c1], p[1200 + c1]}; }
    REP25(R1_LD)
#undef R1_LD

    if (k < H1) hs[k] = 0.0f;
    float cst = 0.0f;
    float zc0 = zx[(size_t)row * 400 + c0];
    float zc1 = zx[(size_t)row * 400 + c1];
    __syncthreads();

    for (int t = 0; t < T_SEQ; ++t) {
        // prefetch next step's zx
        int tn = (t + 1 < T_SEQ) ? t + 1 : t;
        const float* pz = &zx[((size_t)tn * BATCH + row) * 400];
        float zn0 = pz[c0];
        float zn1 = pz[c1];

        f4v s0 = {0.f, 0.f, 0.f, 0.f};
        f4v s1 = {0.f, 0.f, 0.f, 0.f};
#define R1_FMA(i) { f4v hv = *(const f4v*)&hs[4 * i]; s0 += hv * u0_##i; s1 += hv * u1_##i; }
        REP25(R1_FMA)
#undef R1_FMA
        float a0 = sigmoidf_(zc0 + hsum4_(s0));                    // i or f
        float a1h = zc1 + hsum4_(s1);
        float a1 = (k < H1) ? fmaxf(a1h, 0.0f) : sigmoidf_(a1h);   // g (relu) or o
        if (k >= H1 && k < 200) *(float2*)&fo[2 * (k - H1)] = make_float2(a0, a1);
        __syncthreads();

        if (k < H1) {
            float2 f_o = *(const float2*)&fo[2 * k];
            cst = f_o.x * cst + a0 * a1;          // c = f*c + i*g
            float h = f_o.y * fmaxf(cst, 0.0f);   // h = o*relu(c)
            hs[k] = h;
            h1seq[((size_t)t * BATCH + row) * H1 + k] = h;
        }
        __syncthreads();
        zc0 = zn0;
        zc1 = zn1;
    }
}

// =================== recurrence, layer 2 (time-chunked) ===================
// 4-way k-split: thread (kq=tid>>7, cl=tid&127) covers k in [kq*32,kq*32+32)
// for cols {cl, cl+128, cl+256, cl+384}. 32 f4v SSA weights (128 VGPRs).
// waves_per_eu(2,2): 8-wave block -> 2 waves/EU exactly -> 256-VGPR budget.
template<bool INIT, bool LAST>
__global__ __launch_bounds__(512)
__attribute__((amdgpu_waves_per_eu(2, 2)))
void rec2_chunk(const float* __restrict__ zx,    // [tlen][B][512] (bias included)
                const float* __restrict__ U2,    // [128][512]
                float* __restrict__ cbuf,        // [B][128]
                float* __restrict__ hbuf,        // [B][128]
                float* __restrict__ h2out,       // [B][128] (used when LAST)
                int tlen)
{
    const int row = blockIdx.x;
    const int tid = threadIdx.x;   // 0..511
    const int kq = tid >> 7;
    const int cl = tid & 127;
    __shared__ __align__(16) float hs[H2];
    __shared__ float zp[4 * 512];
    __shared__ float za[512];

#define R2_LD(j) \
    f4v w0_##j, w1_##j, w2_##j, w3_##j; { \
        const float* p = U2 + (size_t)(kq * 32 + 4 * j) * 512 + cl; \
        w0_##j = (f4v){p[0],   p[512],       p[1024],       p[1536]}; \
        w1_##j = (f4v){p[128], p[512 + 128], p[1024 + 128], p[1536 + 128]}; \
        w2_##j = (f4v){p[256], p[512 + 256], p[1024 + 256], p[1536 + 256]}; \
        w3_##j = (f4v){p[384], p[512 + 384], p[1024 + 384], p[1536 + 384]}; }
    REP8(R2_LD)
#undef R2_LD

    float cst = 0.0f;
    if (tid < H2) {
        if (INIT) {
            hs[tid] = 0.0f;
        } else {
            hs[tid] = hbuf[(size_t)row * H2 + tid];
            cst = cbuf[(size_t)row * H2 + tid];
        }
    }
    float zc = zx[(size_t)row * 512 + tid];
    __syncthreads();

    for (int t = 0; t < tlen; ++t) {
        int tn = (t + 1 < tlen) ? t + 1 : t;
        float zn = zx[((size_t)tn * BATCH + row) * 512 + tid];

        f4v s0 = {0.f, 0.f, 0.f, 0.f};
        f4v s1 = {0.f, 0.f, 0.f, 0.f};
        f4v s2 = {0.f, 0.f, 0.f, 0.f};
        f4v s3 = {0.f, 0.f, 0.f, 0.f};
#define R2_FMA(j) { f4v hv = *(const f4v*)&hs[kq * 32 + 4 * j]; \
        s0 += hv * w0_##j; s1 += hv * w1_##j; s2 += hv * w2_##j; s3 += hv * w3_##j; }
        REP8(R2_FMA)
#undef R2_FMA
        zp[kq * 512 + cl]       = hsum4_(s0);
        zp[kq * 512 + cl + 128] = hsum4_(s1);
        zp[kq * 512 + cl + 256] = hsum4_(s2);
        zp[kq * 512 + cl + 384] = hsum4_(s3);
        __syncthreads();

        float z = zc + (zp[tid] + zp[512 + tid]) + (zp[1024 + tid] + zp[1536 + tid]);
        float a = (tid >= 2 * H2 && tid < 3 * H2) ? fmaxf(z, 0.0f) : sigmoidf_(z);
        za[tid] = a;
        __syncthreads();

        if (tid < H2) {
            float i = za[tid], f = za[tid + 128], g = za[tid + 256], o = za[tid + 384];
            cst = f * cst + i * g;
            hs[tid] = o * fmaxf(cst, 0.0f);
        }
        __syncthreads();
        zc = zn;
    }

    if (tid < H2) {
        float h = hs[tid];
        cbuf[(size_t)row * H2 + tid] = cst;
        hbuf[(size_t)row * H2 + tid] = h;
        if (LAST) h2out[(size_t)row * H2 + tid] = h;
    }
}

// =================== dense + softmax ===================
__global__ __launch_bounds__(64, 1)
void dense_softmax_kernel(const float* __restrict__ h2, const float* __restrict__ Wd,
                          const float* __restrict__ bd, float* __restrict__ out)
{
    const int b = blockIdx.x;
    const int k = threadIdx.x;
    __shared__ __align__(16) float hsm[H2];
    if (k < H2 / 4) ((f4v*)hsm)[k] = ((const f4v*)(h2 + (size_t)b * H2))[k];
    __syncthreads();

    float logit = -1e30f;
    if (k < NCLS) {
        float acc = bd[k];
#pragma unroll
        for (int d = 0; d < H2; ++d) acc += hsm[d] * Wd[d * NCLS + k];
        logit = acc;
    }
    float m = logit;
#pragma unroll
    for (int off = 32; off >= 1; off >>= 1) m = fmaxf(m, __shfl_xor(m, off, 64));
    float e = (k < NCLS) ? __expf(logit - m) : 0.0f;
    float s = e;
#pragma unroll
    for (int off = 32; off >= 1; off >>= 1) s += __shfl_xor(s, off, 64);
    if (k < NCLS) out[(size_t)b * NCLS + k] = e / s;
}

// =================== fallback (round-1) kernels ===================
__global__ __launch_bounds__(448, 1)
void lstm1_fb(const float* __restrict__ x, const float* __restrict__ W1,
              const float* __restrict__ U1, const float* __restrict__ b1,
              float* __restrict__ h1out)
{
    const int b = blockIdx.x;
    const int k = threadIdx.x;
    __shared__ __align__(16) float xs[IN_DIM];
    __shared__ __align__(16) float hs[H1];
    __shared__ __align__(16) float zs[4 * H1];
    float w1r[IN_DIM];
    float u1r[H1];
    float bias = 0.0f;
    if (k < 4 * H1) {
        bias = b1[k];
#pragma unroll
        for (int d = 0; d < IN_DIM; ++d) w1r[d] = W1[d * (4 * H1) + k];
#pragma unroll
        for (int j = 0; j < H1; ++j) u1r[j] = U1[j * (4 * H1) + k];
    }
    if (k < H1) hs[k] = 0.0f;
    if (k < IN_DIM / 4)
        ((float4*)xs)[k] = ((const float4*)(x + ((size_t)b * T_SEQ) * IN_DIM))[k];
    float c = 0.0f;
    __syncthreads();
    for (int t = 0; t < T_SEQ; ++t) {
        if (k < 4 * H1) {
            float acc0 = bias, acc1 = 0.f, acc2 = 0.f, acc3 = 0.f;
#pragma unroll
            for (int q = 0; q < IN_DIM / 4; ++q) {
                float4 xv = ((const float4*)xs)[q];
                acc0 += xv.x * w1r[4 * q]; acc1 += xv.y * w1r[4 * q + 1];
                acc2 += xv.z * w1r[4 * q + 2]; acc3 += xv.w * w1r[4 * q + 3];
            }
#pragma unroll
            for (int q = 0; q < H1 / 4; ++q) {
                float4 hv = ((const float4*)hs)[q];
                acc0 += hv.x * u1r[4 * q]; acc1 += hv.y * u1r[4 * q + 1];
                acc2 += hv.z * u1r[4 * q + 2]; acc3 += hv.w * u1r[4 * q + 3];
            }
            float zv = (acc0 + acc1) + (acc2 + acc3);
            zs[k] = (k >= 2 * H1 && k < 3 * H1) ? fmaxf(zv, 0.0f) : sigmoidf_(zv);
        }
        __syncthreads();
        if (k < H1) {
            float i = zs[k], f = zs[k + H1], g = zs[k + 2 * H1], o = zs[k + 3 * H1];
            c = f * c + i * g;
            float h = o * fmaxf(c, 0.0f);
            hs[k] = h;
            h1out[((size_t)t * BATCH + b) * H1 + k] = h;
        }
        int tn = t + 1;
        if (tn < T_SEQ && k < IN_DIM / 4)
            ((float4*)xs)[k] = ((const float4*)(x + ((size_t)b * T_SEQ + tn) * IN_DIM))[k];
        __syncthreads();
    }
}

__global__ __launch_bounds__(512, 1)
void lstm2_fb(const float* __restrict__ h1in, const float* __restrict__ W2,
              const float* __restrict__ U2, const float* __restrict__ b2,
              float* __restrict__ h2out)
{
    const int b = blockIdx.x;
    const int k = threadIdx.x;
    __shared__ __align__(16) float ps[H1];
    __shared__ __align__(16) float hs[H2];
    __shared__ __align__(16) float zs[4 * H2];
    float w2r[H1];
    float u2r[H2];
    float bias = b2[k];
#pragma unroll
    for (int j = 0; j < H1; ++j) w2r[j] = W2[j * (4 * H2) + k];
#pragma unroll
    for (int j = 0; j < H2; ++j) u2r[j] = U2[j * (4 * H2) + k];
    if (k < H2) hs[k] = 0.0f;
    if (k < H1 / 4)
        ((float4*)ps)[k] = ((const float4*)(h1in + (size_t)b * H1))[k];
    float c = 0.0f;
    float hlast = 0.0f;
    __syncthreads();
    for (int t = 0; t < T_SEQ; ++t) {
        float acc0 = bias, acc1 = 0.f, acc2 = 0.f, acc3 = 0.f;
#pragma unroll
        for (int q = 0; q < H1 / 4; ++q) {
            float4 pv = ((const float4*)ps)[q];
            acc0 += pv.x * w2r[4 * q]; acc1 += pv.y * w2r[4 * q + 1];
            acc2 += pv.z * w2r[4 * q + 2]; acc3 += pv.w * w2r[4 * q + 3];
        }
#pragma unroll
        for (int q = 0; q < H2 / 4; ++q) {
            float4 hv = ((const float4*)hs)[q];
            acc0 += hv.x * u2r[4 * q]; acc1 += hv.y * u2r[4 * q + 1];
            acc2 += hv.z * u2r[4 * q + 2]; acc3 += hv.w * u2r[4 * q + 3];
        }
        float zv = (acc0 + acc1) + (acc2 + acc3);
        zs[k] = (k >= 2 * H2 && k < 3 * H2) ? fmaxf(zv, 0.0f) : sigmoidf_(zv);
        __syncthreads();
        if (k < H2) {
            float i = zs[k], f = zs[k + H2], g = zs[k + 2 * H2], o = zs[k + 3 * H2];
            c = f * c + i * g;
            hlast = o * fmaxf(c, 0.0f);
            hs[k] = hlast;
        }
        int tn = t + 1;
        if (tn < T_SEQ && k < H1 / 4)
            ((float4*)ps)[k] = ((const float4*)(h1in + ((size_t)tn * BATCH + b) * H1))[k];
        __syncthreads();
    }
    if (k < H2) h2out[(size_t)b * H2 + k] = hlast;
}

extern "C" void kernel_launch(void* const* d_in, const int* in_sizes, int n_in,
                              void* d_out, int out_size, void* d_ws, size_t ws_size,
                              hipStream_t stream) {
    const float* x  = (const float*)d_in[0];
    const float* W1 = (const float*)d_in[1];
    const float* U1 = (const float*)d_in[2];
    const float* b1 = (const float*)d_in[3];
    const float* W2 = (const float*)d_in[4];
    const float* U2 = (const float*)d_in[5];
    const float* b2 = (const float*)d_in[6];
    const float* Wd = (const float*)d_in[7];
    const float* bd = (const float*)d_in[8];
    float* out = (float*)d_out;

    const size_t zx_elems = (size_t)T_SEQ * BATCH * 400;   // 52428800
    const size_t h1_elems = (size_t)T_SEQ * BATCH * H1;    // 13107200
    const size_t st_elems = (size_t)BATCH * H2;            // 65536
    const size_t need = (zx_elems + h1_elems + 3 * st_elems) * sizeof(float);  // 262.93 MB

    if (ws_size >= need) {
        float* zxbuf = (float*)d_ws;
        float* h1buf = zxbuf + zx_elems;
        float* cbuf  = h1buf + h1_elems;
        float* hbuf  = cbuf + st_elems;
        float* h2buf = hbuf + st_elems;
        const int TC = T_SEQ / 2;   // 128-step chunks

        // zx1 = x @ W1 + b1 -> [T][B][400]
        hipLaunchKernelGGL((proj_kernel<IN_DIM, 4 * H1, true>), dim3(1024, 4), dim3(256), 0, stream,
                           x, W1, b1, zxbuf);
        hipLaunchKernelGGL(rec1_kernel, dim3(BATCH), dim3(256), 0, stream,
                           zxbuf, U1, h1buf);
        // ---- layer 2, chunk A (t = 0..127): zx2 chunk overwrites zx1 region ----
        hipLaunchKernelGGL((proj_kernel<H1, 4 * H2, false>), dim3(512, 4), dim3(256), 0, stream,
                           h1buf, W2, b2, zxbuf);
        hipLaunchKernelGGL((rec2_chunk<true, false>), dim3(BATCH), dim3(512), 0, stream,
                           zxbuf, U2, cbuf, hbuf, h2buf, TC);
        // ---- layer 2, chunk B (t = 128..255) ----
        hipLaunchKernelGGL((proj_kernel<H1, 4 * H2, false>), dim3(512, 4), dim3(256), 0, stream,
                           h1buf + (size_t)TC * BATCH * H1, W2, b2, zxbuf);
        hipLaunchKernelGGL((rec2_chunk<false, true>), dim3(BATCH), dim3(512), 0, stream,
                           zxbuf, U2, cbuf, hbuf, h2buf, TC);

        hipLaunchKernelGGL(dense_softmax_kernel, dim3(BATCH), dim3(64), 0, stream,
                           h2buf, Wd, bd, out);
    } else {
        // fallback: round-1 fused kernels (needs ~52.7 MB)
        float* h1buf = (float*)d_ws;
        float* h2buf = h1buf + h1_elems;
        hipLaunchKernelGGL(lstm1_fb, dim3(BATCH), dim3(448), 0, stream, x, W1, U1, b1, h1buf);
        hipLaunchKernelGGL(lstm2_fb, dim3(BATCH), dim3(512), 0, stream, h1buf, W2, U2, b2, h2buf);
        hipLaunchKernelGGL(dense_softmax_kernel, dim3(BATCH), dim3(64), 0, stream, h2buf, Wd, bd, out);
    }
}